// Round 3
// baseline (165.899 us; speedup 1.0000x reference)
//
#include <hip/hip_runtime.h>

// Problem constants (from reference): B=4, T=512, S=256, V=50257.
#define DIM_B 4
#define DIM_T 512
#define DIM_S 256
#define DIM_V 50257

#define HSZ   512          // LDS hash slots (load factor <= 0.5)
#define HMSK  (HSZ - 1)
#define NBMW  393          // bitmap words: ceil(max_nvec=12564 / 32)

// Single-pass fused kernel: one block per output row (b,t).
//  1. Build LDS hash v_idx -> sum(val) for the row's 256 scatter entries
//     (open addressing + LDS atomics; duplicates accumulate exactly).
//  2. Build LDS bitmap of which float4 chunks contain a scatter target.
//  3. Stream the row once: float4 zero stores, flagged chunks (~2%) compose
//     their lanes from the hash. Every output byte written exactly once ->
//     HBM traffic = 412 MB write + 2 MB read, no atomics, no RMW refetch.
__global__ __launch_bounds__(256) void merge_onepass_kernel(
    const float* __restrict__ p_pos,   // [B, T, S]
    const int*   __restrict__ src,     // [B, S]  (int64 narrowed to int32)
    float*       __restrict__ out)     // [B, T, V]
{
    __shared__ int      h_key[HSZ];
    __shared__ float    h_val[HSZ];
    __shared__ unsigned bm[NBMW];

    const int row = blockIdx.x;        // row = b*T + t
    const int b   = row / DIM_T;
    const int tid = threadIdx.x;

    // ---- row geometry (alignment-safe float4 middle + scalar head/tail) ----
    // base_elems % 4 == row % 4 (since 50257 % 4 == 1)
    const int head = (4 - (row & 3)) & 3;          // scalar elems before aligned middle
    const int nvec = (DIM_V - head) >> 2;          // float4 chunks
    const int tail_start = head + (nvec << 2);
    const int ntail = DIM_V - tail_start;          // 0..3

    // ---- init LDS ----
    for (int i = tid; i < HSZ; i += 256) { h_key[i] = -1; h_val[i] = 0.0f; }
    for (int i = tid; i < NBMW; i += 256) bm[i] = 0u;
    __syncthreads();

    // ---- insert the row's 256 (v, p) pairs ----
    {
        const int   v = src[b * DIM_S + tid];
        const float p = p_pos[(size_t)row * DIM_S + tid];
        int h = v & HMSK;
        while (true) {
            int prev = atomicCAS(&h_key[h], -1, v);
            if (prev == -1 || prev == v) { atomicAdd(&h_val[h], p); break; }
            h = (h + 1) & HMSK;
        }
        if (v >= head && v < tail_start) {
            const int c = (v - head) >> 2;         // chunk containing v
            atomicOr(&bm[c >> 5], 1u << (c & 31));
        }
    }
    __syncthreads();

    // ---- hash lookup (table is read-only past this point) ----
    auto lookup = [&](int v) -> float {
        int h = v & HMSK;
        while (true) {
            const int k = h_key[h];
            if (k == v)  return h_val[h];
            if (k == -1) return 0.0f;
            h = (h + 1) & HMSK;
        }
    };

    float* __restrict__ row_ptr = out + (size_t)row * DIM_V;

    // scalar head / tail (rarely scatter targets, lookup unconditionally)
    if (tid < head)  row_ptr[tid] = lookup(tid);
    if (tid < ntail) row_ptr[tail_start + tid] = lookup(tail_start + tid);

    // ---- single streaming pass over the aligned middle ----
    float4* __restrict__ vp = (float4*)(row_ptr + head);
    const float4 z = make_float4(0.0f, 0.0f, 0.0f, 0.0f);
    for (int c = tid; c < nvec; c += 256) {
        const unsigned w = bm[c >> 5];
        float4 o = z;
        if ((w >> (c & 31)) & 1u) {                // ~2% of chunks
            const int v0 = head + (c << 2);
            o.x = lookup(v0);
            o.y = lookup(v0 + 1);
            o.z = lookup(v0 + 2);
            o.w = lookup(v0 + 3);
        }
        vp[c] = o;
    }
}

extern "C" void kernel_launch(void* const* d_in, const int* in_sizes, int n_in,
                              void* d_out, int out_size, void* d_ws, size_t ws_size,
                              hipStream_t stream) {
    const float* p_pos = (const float*)d_in[0];   // [B,T,S]
    // d_in[1] = p_target_vocab — dead data (shape-only in the reference).
    const int*   src   = (const int*)d_in[2];     // [B,S]
    float*       out   = (float*)d_out;           // [B,T,V]

    merge_onepass_kernel<<<DIM_B * DIM_T, DIM_S, 0, stream>>>(p_pos, src, out);
}